// Round 1
// baseline (142.829 us; speedup 1.0000x reference)
//
#include <hip/hip_runtime.h>

// PointNet++ grouping: ball query (radius 0.2, nsample 64) + gather + concat.
// Shapes fixed by setup_inputs(): B=4, N=16384, npoint=2048, C=64.
// out[b][j][c][s]: c in [0,3) = xyz[idx]-new_xyz, c in [3,67) = features[c-3][idx].

#define BB 4
#define NN 16384
#define NP 2048
#define CC 64
#define NS 64
#define CH (3 + CC)
#define WAVES_PER_BLOCK 4

__global__ __launch_bounds__(256, 4) void pn2_group_kernel(
    const float* __restrict__ xyz,       // (B, N, 3)
    const float* __restrict__ new_xyz,   // (B, NP, 3)
    const float* __restrict__ features,  // (B, C, N)
    float* __restrict__ out)             // (B, NP, CH, NS)
{
    __shared__ int sidx[WAVES_PER_BLOCK][NS];

    const int lane = threadIdx.x & 63;
    const int wave = threadIdx.x >> 6;
    const int center = blockIdx.x * WAVES_PER_BLOCK + wave;  // 0 .. B*NP-1
    const int b = center >> 11;        // / NP (NP = 2048)
    const int j = center & (NP - 1);   // % NP

    // threshold: f32(0.2*0.2) == 0.04f
    const float r2 = 0.04f;
    const float* q = new_xyz + ((size_t)b * NP + j) * 3;
    const float cx = q[0], cy = q[1], cz = q[2];

    int* widx = sidx[wave];

    // ---- Phase 1: ball query, strict index order via ballot + prefix popcount
    int found = 0;
    for (int it = 0; it < NN / 64; ++it) {
        const int n = it * 64 + lane;
        const float* p = xyz + ((size_t)b * NN + n) * 3;
        const float dx = p[0] - cx;
        const float dy = p[1] - cy;
        const float dz = p[2] - cz;
        // match numpy/JAX: plain f32 mul/add, left-to-right, NO fma contraction
        const float d2 = __fadd_rn(__fadd_rn(__fmul_rn(dx, dx), __fmul_rn(dy, dy)),
                                   __fmul_rn(dz, dz));
        const bool within = d2 < r2;
        const unsigned long long mask = __ballot(within);
        const int prior = (int)__popcll(mask & ((1ull << lane) - 1ull));
        const int pos = found + prior;
        if (within && pos < NS) widx[pos] = n;
        found += (int)__popcll(mask);   // wave-uniform
        if (found >= NS) break;         // uniform branch
    }

    // ---- slot -> index (reference fill semantics: pad with first found, 0 if none)
    int myidx = 0;
    if (found > 0) {
        const int first = widx[0];
        myidx = (lane < found) ? widx[lane] : first;
    }

    // ---- Phase 2: gather + write. lane == sample slot s; stores are 256B coalesced.
    const float* pp = xyz + ((size_t)b * NN + myidx) * 3;
    const float gx = pp[0] - cx;
    const float gy = pp[1] - cy;
    const float gz = pp[2] - cz;

    float* ob = out + (((size_t)b * NP + j) * (size_t)CH) * NS + lane;
    ob[0 * NS] = gx;
    ob[1 * NS] = gy;
    ob[2 * NS] = gz;

    const float* fb = features + (size_t)b * CC * NN + myidx;
#pragma unroll 8
    for (int c = 0; c < CC; ++c) {
        ob[(size_t)(3 + c) * NS] = fb[(size_t)c * NN];
    }
}

extern "C" void kernel_launch(void* const* d_in, const int* in_sizes, int n_in,
                              void* d_out, int out_size, void* d_ws, size_t ws_size,
                              hipStream_t stream) {
    const float* xyz      = (const float*)d_in[0];
    const float* new_xyz  = (const float*)d_in[1];
    const float* features = (const float*)d_in[2];
    float* out = (float*)d_out;

    const int total_centers = BB * NP;                       // 8192
    const int blocks = total_centers / WAVES_PER_BLOCK;      // 2048
    pn2_group_kernel<<<blocks, 256, 0, stream>>>(xyz, new_xyz, features, out);
}

// Round 2
// 60.956 us; speedup vs baseline: 2.3431x; 2.3431x over previous
//
#include <hip/hip_runtime.h>

// PointNet++ grouping: ball query (radius 0.2, nsample 64) + gather + concat.
// Shapes fixed by setup_inputs(): B=4, N=16384, npoint=2048, C=64.
// out[b][j][c][s]: c in [0,3) = xyz[idx]-new_xyz, c in [3,67) = features[c-3][idx].
//
// Strategy: (1) transpose features (B,C,N)->(B,N,C) into d_ws so the
// per-sample channel gather is a contiguous 256B row (16x less L1/L2 line
// traffic than the strided gather); (2) ball-query scans 256 points per
// iteration with all loads issued up-front (4x less latency exposure on the
// rare full-scan corner centers).

#define BB 4
#define NN 16384
#define NP 2048
#define CC 64
#define NS 64
#define CH (3 + CC)
#define WPB 4  // waves per block

// ---------- Kernel 1: features (B,C,N) -> ft (B,N,C) ----------
__global__ __launch_bounds__(256) void pn2_transpose_kernel(
    const float* __restrict__ f, float* __restrict__ ft)
{
    __shared__ float tile[CC][65];           // +1 pad: conflict-free both ways
    const int b   = blockIdx.x >> 8;         // N/64 = 256 tiles per batch
    const int n0  = (blockIdx.x & 255) << 6;
    const int col = threadIdx.x & 63;
    const int r4  = threadIdx.x >> 6;        // 0..3
    const float* src = f + (size_t)b * CC * NN;
#pragma unroll
    for (int i = 0; i < 16; ++i) {
        const int c = r4 + i * 4;
        tile[c][col] = src[(size_t)c * NN + n0 + col];   // coalesced along n
    }
    __syncthreads();
    float* dst = ft + ((size_t)b * NN + n0) * CC;
#pragma unroll
    for (int i = 0; i < 16; ++i) {
        const int n = r4 + i * 4;
        dst[(size_t)n * CC + col] = tile[col][n];        // coalesced along c
    }
}

// ---------- Kernel 2: ball query + gather (transposed features) ----------
__global__ __launch_bounds__(256, 4) void pn2_group_t_kernel(
    const float* __restrict__ xyz,       // (B, N, 3)
    const float* __restrict__ new_xyz,   // (B, NP, 3)
    const float* __restrict__ ft,        // (B, N, C) transposed
    float* __restrict__ out)             // (B, NP, CH, NS)
{
    __shared__ int sidx[WPB][NS];

    const int lane = threadIdx.x & 63;
    const int wave = threadIdx.x >> 6;
    const int center = blockIdx.x * WPB + wave;   // 0 .. B*NP-1
    const int b = center >> 11;                   // / NP
    const int j = center & (NP - 1);              // % NP

    const float r2 = 0.04f;                       // f32(0.2*0.2)
    const float* q = new_xyz + ((size_t)b * NP + j) * 3;
    const float cx = q[0], cy = q[1], cz = q[2];

    int* widx = sidx[wave];
    const float* xb = xyz + (size_t)b * NN * 3;

    // ---- Phase 1: ball query, strict index order; 256 points per iteration
    int found = 0;
    for (int it = 0; it < NN / 256; ++it) {
        const int n0 = it * 256 + lane;
        float px[4], py[4], pz[4];
#pragma unroll
        for (int k = 0; k < 4; ++k) {             // all 12 loads in flight
            const float* p = xb + (size_t)(n0 + k * 64) * 3;
            px[k] = p[0]; py[k] = p[1]; pz[k] = p[2];
        }
#pragma unroll
        for (int k = 0; k < 4; ++k) {
            const float dx = px[k] - cx;
            const float dy = py[k] - cy;
            const float dz = pz[k] - cz;
            // match numpy: plain f32 mul/add, left-to-right, NO fma contraction
            const float d2 = __fadd_rn(__fadd_rn(__fmul_rn(dx, dx), __fmul_rn(dy, dy)),
                                       __fmul_rn(dz, dz));
            const bool within = d2 < r2;
            const unsigned long long mask = __ballot(within);
            const int pos = found + (int)__popcll(mask & ((1ull << lane) - 1ull));
            if (within && pos < NS) widx[pos] = n0 + k * 64;
            found += (int)__popcll(mask);         // wave-uniform
        }
        if (found >= NS) break;                   // uniform branch
    }

    // ---- slot -> index (ref fill semantics: pad with first found, 0 if none)
    int myidx = 0;
    if (found > 0) {
        const int first = widx[0];
        myidx = (lane < found) ? widx[lane] : first;
    }

    // ---- Phase 2: gather. lane == sample slot; contiguous 256B feature row.
    const float* pp = xb + (size_t)myidx * 3;
    const float gx = pp[0] - cx;
    const float gy = pp[1] - cy;
    const float gz = pp[2] - cz;

    const float4* frow = (const float4*)(ft + ((size_t)b * NN + myidx) * CC);
    float4 v[16];
#pragma unroll
    for (int i = 0; i < 16; ++i) v[i] = frow[i];  // 16 loads in flight, 16B each

    float* ob = out + (((size_t)b * NP + j) * (size_t)CH) * NS + lane;
    ob[0 * NS] = gx;
    ob[1 * NS] = gy;
    ob[2 * NS] = gz;
#pragma unroll
    for (int i = 0; i < 16; ++i) {                // 256B-coalesced stores
        ob[(size_t)(3 + 4 * i + 0) * NS] = v[i].x;
        ob[(size_t)(3 + 4 * i + 1) * NS] = v[i].y;
        ob[(size_t)(3 + 4 * i + 2) * NS] = v[i].z;
        ob[(size_t)(3 + 4 * i + 3) * NS] = v[i].w;
    }
}

// ---------- Fallback (ws too small): round-1 direct-gather kernel ----------
__global__ __launch_bounds__(256, 4) void pn2_group_kernel(
    const float* __restrict__ xyz, const float* __restrict__ new_xyz,
    const float* __restrict__ features, float* __restrict__ out)
{
    __shared__ int sidx[WPB][NS];
    const int lane = threadIdx.x & 63;
    const int wave = threadIdx.x >> 6;
    const int center = blockIdx.x * WPB + wave;
    const int b = center >> 11;
    const int j = center & (NP - 1);
    const float r2 = 0.04f;
    const float* q = new_xyz + ((size_t)b * NP + j) * 3;
    const float cx = q[0], cy = q[1], cz = q[2];
    int* widx = sidx[wave];
    int found = 0;
    for (int it = 0; it < NN / 64; ++it) {
        const int n = it * 64 + lane;
        const float* p = xyz + ((size_t)b * NN + n) * 3;
        const float dx = p[0] - cx, dy = p[1] - cy, dz = p[2] - cz;
        const float d2 = __fadd_rn(__fadd_rn(__fmul_rn(dx, dx), __fmul_rn(dy, dy)),
                                   __fmul_rn(dz, dz));
        const bool within = d2 < r2;
        const unsigned long long mask = __ballot(within);
        const int pos = found + (int)__popcll(mask & ((1ull << lane) - 1ull));
        if (within && pos < NS) widx[pos] = n;
        found += (int)__popcll(mask);
        if (found >= NS) break;
    }
    int myidx = 0;
    if (found > 0) {
        const int first = widx[0];
        myidx = (lane < found) ? widx[lane] : first;
    }
    const float* pp = xyz + ((size_t)b * NN + myidx) * 3;
    float* ob = out + (((size_t)b * NP + j) * (size_t)CH) * NS + lane;
    ob[0 * NS] = pp[0] - cx;
    ob[1 * NS] = pp[1] - cy;
    ob[2 * NS] = pp[2] - cz;
    const float* fb = features + (size_t)b * CC * NN + myidx;
#pragma unroll 8
    for (int c = 0; c < CC; ++c) ob[(size_t)(3 + c) * NS] = fb[(size_t)c * NN];
}

extern "C" void kernel_launch(void* const* d_in, const int* in_sizes, int n_in,
                              void* d_out, int out_size, void* d_ws, size_t ws_size,
                              hipStream_t stream) {
    const float* xyz      = (const float*)d_in[0];
    const float* new_xyz  = (const float*)d_in[1];
    const float* features = (const float*)d_in[2];
    float* out = (float*)d_out;

    const size_t need = (size_t)BB * NN * CC * sizeof(float);  // 16.8 MB
    const int gblocks = BB * NP / WPB;                          // 2048

    if (ws_size >= need) {
        float* ft = (float*)d_ws;
        pn2_transpose_kernel<<<BB * 256, 256, 0, stream>>>(features, ft);
        pn2_group_t_kernel<<<gblocks, 256, 0, stream>>>(xyz, new_xyz, ft, out);
    } else {
        pn2_group_kernel<<<gblocks, 256, 0, stream>>>(xyz, new_xyz, features, out);
    }
}

// Round 3
// 54.516 us; speedup vs baseline: 2.6200x; 1.1181x over previous
//
#include <hip/hip_runtime.h>

// PointNet++ grouping: ball query (radius 0.2, nsample 64) + gather + concat.
// Shapes fixed by setup_inputs(): B=4, N=16384, npoint=2048, C=64.
// out[b][j][c][s]: c in [0,3) = xyz[idx]-new_xyz, c in [3,67) = features[c-3][idx].
//
// Pipeline:
//   Kernel A (fused, independent block roles):
//     blocks [0,1024):    transpose features (B,C,N) -> ft (B,N,C) in ws
//     blocks [1024,3072): ball query (4 pts/lane, float4 loads, prefetch);
//                         writes idx (with ref fill semantics) to ws and the
//                         3 xyz output channels.
//   Kernel B: gather — 1 block per center, wave w = 16 channels; per wave:
//     coalesced idx load + 4x dwordx4 row gather + 16x 256B coalesced
//     nontemporal stores. No query latency -> write-BW bound.

#define BB 4
#define NN 16384
#define NP 2048
#define CC 64
#define NS 64
#define CH (3 + CC)
#define NCHUNK (NN / 256)   // 64 chunks of 256 points

// ---------- Kernel A: transpose + ball query ----------
__global__ __launch_bounds__(256) void pn2_prep_kernel(
    const float* __restrict__ xyz,       // (B, N, 3)
    const float* __restrict__ new_xyz,   // (B, NP, 3)
    const float* __restrict__ features,  // (B, C, N)
    float* __restrict__ ft,              // ws: (B, N, C)
    int* __restrict__ idxbuf,            // ws: (B*NP, NS)
    float* __restrict__ out)             // (B, NP, CH, NS)
{
    __shared__ float tile[CC][65];
    __shared__ int sidx[4][NS];

    if (blockIdx.x < BB * 256) {
        // ---- transpose role ----
        const int b   = blockIdx.x >> 8;
        const int n0  = (blockIdx.x & 255) << 6;
        const int col = threadIdx.x & 63;
        const int r4  = threadIdx.x >> 6;
        const float* src = features + (size_t)b * CC * NN;
#pragma unroll
        for (int i = 0; i < 16; ++i) {
            const int c = r4 + i * 4;
            tile[c][col] = src[(size_t)c * NN + n0 + col];   // coalesced along n
        }
        __syncthreads();
        float* dst = ft + ((size_t)b * NN + n0) * CC;
#pragma unroll
        for (int i = 0; i < 16; ++i) {
            const int n = r4 + i * 4;
            dst[(size_t)n * CC + col] = tile[col][n];        // coalesced along c
        }
        return;
    }

    // ---- ball-query role: one wave per center, 4 points per lane ----
    const int lane = threadIdx.x & 63;
    const int wave = threadIdx.x >> 6;
    const int center = (blockIdx.x - BB * 256) * 4 + wave;   // 0 .. B*NP-1
    const int b = center >> 11;
    const int j = center & (NP - 1);

    const float r2 = 0.04f;                                  // f32(0.2*0.2)
    const float* q = new_xyz + ((size_t)b * NP + j) * 3;
    const float cx = q[0], cy = q[1], cz = q[2];

    const float* xb = xyz + (size_t)b * NN * 3;
    const float4* x4 = (const float4*)xb;
    int* widx = sidx[wave];

    // lane l owns points {4l, 4l+1, 4l+2, 4l+3} of each 256-point chunk:
    // 48B = 3x float4, fully coalesced.
    const int base = 3 * lane;
    int found = 0;
    int it = 0;
    float4 A = x4[base], Bv = x4[base + 1], Cv = x4[base + 2];

    while (true) {
        // prefetch next chunk (clamped) before processing current
        const int nit = (it + 1 < NCHUNK) ? it + 1 : it;
        const size_t nb = (size_t)nit * 192 + base;
        float4 nA = x4[nb], nB = x4[nb + 1], nC = x4[nb + 2];

        const int n0 = it * 256 + 4 * lane;
        const float px[4] = {A.x, A.w, Bv.z, Cv.y};
        const float py[4] = {A.y, Bv.x, Bv.w, Cv.z};
        const float pz[4] = {A.z, Bv.y, Cv.x, Cv.w};
        bool in[4];
        unsigned long long m[4];
#pragma unroll
        for (int k = 0; k < 4; ++k) {
            const float dx = px[k] - cx;
            const float dy = py[k] - cy;
            const float dz = pz[k] - cz;
            // match numpy: plain f32 mul/add, left-to-right, NO fma contraction
            const float d2 = __fadd_rn(__fadd_rn(__fmul_rn(dx, dx), __fmul_rn(dy, dy)),
                                       __fmul_rn(dz, dz));
            in[k] = d2 < r2;
            m[k] = __ballot(in[k]);
        }
        const unsigned long long low = (1ull << lane) - 1ull;
        int pos = found
                + (int)__popcll(m[0] & low) + (int)__popcll(m[1] & low)
                + (int)__popcll(m[2] & low) + (int)__popcll(m[3] & low);
#pragma unroll
        for (int k = 0; k < 4; ++k) {
            if (in[k]) {
                if (pos < NS) widx[pos] = n0 + k;
                ++pos;
            }
        }
        found += (int)(__popcll(m[0]) + __popcll(m[1])
                     + __popcll(m[2]) + __popcll(m[3]));     // wave-uniform
        if (found >= NS || it == NCHUNK - 1) break;          // uniform branch
        A = nA; Bv = nB; Cv = nC; ++it;
    }

    // ref fill semantics: pad with first found idx, 0 if none found
    int myidx = 0;
    if (found > 0) {
        const int first = widx[0];
        myidx = (lane < found) ? widx[lane] : first;
    }
    idxbuf[(size_t)center * NS + lane] = myidx;

    const float* pp = xb + (size_t)myidx * 3;
    float* ob = out + ((size_t)center * CH) * NS + lane;
    __builtin_nontemporal_store(pp[0] - cx, ob + 0 * NS);
    __builtin_nontemporal_store(pp[1] - cy, ob + 1 * NS);
    __builtin_nontemporal_store(pp[2] - cz, ob + 2 * NS);
}

// ---------- Kernel B: feature gather (write-BW bound) ----------
__global__ __launch_bounds__(256) void pn2_gather_kernel(
    const float* __restrict__ ft,        // (B, N, C)
    const int* __restrict__ idxbuf,      // (B*NP, NS)
    float* __restrict__ out)             // (B, NP, CH, NS)
{
    const int center = blockIdx.x;       // 0 .. B*NP-1
    const int b = center >> 11;
    const int lane = threadIdx.x & 63;   // sample slot
    const int w = threadIdx.x >> 6;      // channel quarter: [16w, 16w+16)

    const int myidx = idxbuf[(size_t)center * NS + lane];    // coalesced
    const float4* row = (const float4*)(ft + ((size_t)b * NN + myidx) * CC) + 4 * w;
    const float4 v0 = row[0], v1 = row[1], v2 = row[2], v3 = row[3];

    float* ob = out + ((size_t)center * CH + 3 + 16 * w) * NS + lane;
    __builtin_nontemporal_store(v0.x, ob + 0 * NS);
    __builtin_nontemporal_store(v0.y, ob + 1 * NS);
    __builtin_nontemporal_store(v0.z, ob + 2 * NS);
    __builtin_nontemporal_store(v0.w, ob + 3 * NS);
    __builtin_nontemporal_store(v1.x, ob + 4 * NS);
    __builtin_nontemporal_store(v1.y, ob + 5 * NS);
    __builtin_nontemporal_store(v1.z, ob + 6 * NS);
    __builtin_nontemporal_store(v1.w, ob + 7 * NS);
    __builtin_nontemporal_store(v2.x, ob + 8 * NS);
    __builtin_nontemporal_store(v2.y, ob + 9 * NS);
    __builtin_nontemporal_store(v2.z, ob + 10 * NS);
    __builtin_nontemporal_store(v2.w, ob + 11 * NS);
    __builtin_nontemporal_store(v3.x, ob + 12 * NS);
    __builtin_nontemporal_store(v3.y, ob + 13 * NS);
    __builtin_nontemporal_store(v3.z, ob + 14 * NS);
    __builtin_nontemporal_store(v3.w, ob + 15 * NS);
}

// ---------- Fallback (ws too small): round-1 direct-gather kernel ----------
__global__ __launch_bounds__(256, 4) void pn2_group_kernel(
    const float* __restrict__ xyz, const float* __restrict__ new_xyz,
    const float* __restrict__ features, float* __restrict__ out)
{
    __shared__ int sidx[4][NS];
    const int lane = threadIdx.x & 63;
    const int wave = threadIdx.x >> 6;
    const int center = blockIdx.x * 4 + wave;
    const int b = center >> 11;
    const int j = center & (NP - 1);
    const float r2 = 0.04f;
    const float* q = new_xyz + ((size_t)b * NP + j) * 3;
    const float cx = q[0], cy = q[1], cz = q[2];
    int* widx = sidx[wave];
    int found = 0;
    for (int it = 0; it < NN / 64; ++it) {
        const int n = it * 64 + lane;
        const float* p = xyz + ((size_t)b * NN + n) * 3;
        const float dx = p[0] - cx, dy = p[1] - cy, dz = p[2] - cz;
        const float d2 = __fadd_rn(__fadd_rn(__fmul_rn(dx, dx), __fmul_rn(dy, dy)),
                                   __fmul_rn(dz, dz));
        const bool within = d2 < r2;
        const unsigned long long mask = __ballot(within);
        const int pos = found + (int)__popcll(mask & ((1ull << lane) - 1ull));
        if (within && pos < NS) widx[pos] = n;
        found += (int)__popcll(mask);
        if (found >= NS) break;
    }
    int myidx = 0;
    if (found > 0) {
        const int first = widx[0];
        myidx = (lane < found) ? widx[lane] : first;
    }
    const float* pp = xyz + ((size_t)b * NN + myidx) * 3;
    float* ob = out + (((size_t)b * NP + j) * (size_t)CH) * NS + lane;
    ob[0 * NS] = pp[0] - cx;
    ob[1 * NS] = pp[1] - cy;
    ob[2 * NS] = pp[2] - cz;
    const float* fb = features + (size_t)b * CC * NN + myidx;
#pragma unroll 8
    for (int c = 0; c < CC; ++c) ob[(size_t)(3 + c) * NS] = fb[(size_t)c * NN];
}

extern "C" void kernel_launch(void* const* d_in, const int* in_sizes, int n_in,
                              void* d_out, int out_size, void* d_ws, size_t ws_size,
                              hipStream_t stream) {
    const float* xyz      = (const float*)d_in[0];
    const float* new_xyz  = (const float*)d_in[1];
    const float* features = (const float*)d_in[2];
    float* out = (float*)d_out;

    const size_t ft_bytes  = (size_t)BB * NN * CC * sizeof(float);   // 16.8 MB
    const size_t idx_bytes = (size_t)BB * NP * NS * sizeof(int);     //  2.1 MB

    if (ws_size >= ft_bytes + idx_bytes) {
        float* ft   = (float*)d_ws;
        int* idxbuf = (int*)((char*)d_ws + ft_bytes);
        pn2_prep_kernel<<<BB * 256 + BB * NP / 4, 256, 0, stream>>>(
            xyz, new_xyz, features, ft, idxbuf, out);
        pn2_gather_kernel<<<BB * NP, 256, 0, stream>>>(ft, idxbuf, out);
    } else {
        pn2_group_kernel<<<BB * NP / 4, 256, 0, stream>>>(xyz, new_xyz, features, out);
    }
}

// Round 4
// 54.434 us; speedup vs baseline: 2.6239x; 1.0015x over previous
//
#include <hip/hip_runtime.h>

// PointNet++ grouping: ball query (radius 0.2, nsample 64) + gather + concat.
// Shapes fixed by setup_inputs(): B=4, N=16384, npoint=2048, C=64.
// out[b][j][c][s]: c in [0,3) = xyz[idx]-new_xyz, c in [3,67) = features[c-3][idx].
//
// Pipeline:
//   Kernel 1: transpose features (B,C,N) -> ft (B,N,C) in ws (~6 us, BW-bound).
//   Kernel 2: FUSED query+gather, one wave per center. Query leaves myidx in
//     registers; the same wave then gathers its contiguous 256B ft row and
//     writes all 67 channel rows (256B coalesced nontemporal stores). The
//     VALU-heavy query work of long-scan (near-face) centers overlaps other
//     waves' write-BW-bound gather instead of serializing ahead of it.

#define BB 4
#define NN 16384
#define NP 2048
#define CC 64
#define NS 64
#define CH (3 + CC)
#define NCHUNK (NN / 256)   // 64 chunks of 256 points

// ---------- Kernel 1: features (B,C,N) -> ft (B,N,C) ----------
__global__ __launch_bounds__(256) void pn2_transpose_kernel(
    const float* __restrict__ f, float* __restrict__ ft)
{
    __shared__ float tile[CC][65];           // +1 pad: conflict-free both ways
    const int b   = blockIdx.x >> 8;         // N/64 = 256 tiles per batch
    const int n0  = (blockIdx.x & 255) << 6;
    const int col = threadIdx.x & 63;
    const int r4  = threadIdx.x >> 6;        // 0..3
    const float* src = f + (size_t)b * CC * NN;
#pragma unroll
    for (int i = 0; i < 16; ++i) {
        const int c = r4 + i * 4;
        tile[c][col] = __builtin_nontemporal_load(&src[(size_t)c * NN + n0 + col]);
    }
    __syncthreads();
    float* dst = ft + ((size_t)b * NN + n0) * CC;
#pragma unroll
    for (int i = 0; i < 16; ++i) {
        const int n = r4 + i * 4;
        dst[(size_t)n * CC + col] = tile[col][n];        // coalesced along c
    }
}

// ---------- Kernel 2: fused ball query + gather ----------
__global__ __launch_bounds__(256, 4) void pn2_qg_kernel(
    const float* __restrict__ xyz,       // (B, N, 3)
    const float* __restrict__ new_xyz,   // (B, NP, 3)
    const float* __restrict__ ft,        // ws: (B, N, C)
    float* __restrict__ out)             // (B, NP, CH, NS)
{
    __shared__ int sidx[4][NS];

    const int lane = threadIdx.x & 63;
    const int wave = threadIdx.x >> 6;
    const int center = blockIdx.x * 4 + wave;   // 0 .. B*NP-1
    const int b = center >> 11;
    const int j = center & (NP - 1);

    const float r2 = 0.04f;                     // f32(0.2*0.2)
    const float* q = new_xyz + ((size_t)b * NP + j) * 3;
    const float cx = q[0], cy = q[1], cz = q[2];

    const float* xb = xyz + (size_t)b * NN * 3;
    const float4* x4 = (const float4*)xb;
    int* widx = sidx[wave];

    // ---- query: 4 points/lane (48B = 3x float4), prefetch one chunk ahead
    const int base = 3 * lane;
    const unsigned long long low = (1ull << lane) - 1ull;
    int found = 0;
    int it = 0;
    float4 A = x4[base], Bv = x4[base + 1], Cv = x4[base + 2];

    while (true) {
        const int nit = (it + 1 < NCHUNK) ? it + 1 : it;
        const size_t nb = (size_t)nit * 192 + base;
        float4 nA = x4[nb], nB = x4[nb + 1], nC = x4[nb + 2];

        const int n0 = it * 256 + 4 * lane;
        const float px[4] = {A.x, A.w, Bv.z, Cv.y};
        const float py[4] = {A.y, Bv.x, Bv.w, Cv.z};
        const float pz[4] = {A.z, Bv.y, Cv.x, Cv.w};
        bool in[4];
        unsigned long long m[4];
#pragma unroll
        for (int k = 0; k < 4; ++k) {
            const float dx = px[k] - cx;
            const float dy = py[k] - cy;
            const float dz = pz[k] - cz;
            // match numpy: plain f32 mul/add, left-to-right, NO fma contraction
            const float d2 = __fadd_rn(__fadd_rn(__fmul_rn(dx, dx), __fmul_rn(dy, dy)),
                                       __fmul_rn(dz, dz));
            in[k] = d2 < r2;
            m[k] = __ballot(in[k]);
        }
        int pos = found
                + (int)__popcll(m[0] & low) + (int)__popcll(m[1] & low)
                + (int)__popcll(m[2] & low) + (int)__popcll(m[3] & low);
#pragma unroll
        for (int k = 0; k < 4; ++k) {
            if (in[k]) {
                if (pos < NS) widx[pos] = n0 + k;
                ++pos;
            }
        }
        found += (int)(__popcll(m[0]) + __popcll(m[1])
                     + __popcll(m[2]) + __popcll(m[3]));     // wave-uniform
        if (found >= NS || it == NCHUNK - 1) break;          // uniform branch
        A = nA; Bv = nB; Cv = nC; ++it;
    }

    // ref fill semantics: pad with first found idx, 0 if none found
    int myidx = 0;
    if (found > 0) {
        const int first = widx[0];
        myidx = (lane < found) ? widx[lane] : first;
    }

    // ---- gather: lane == sample slot; contiguous 256B ft row per lane
    const float* pp = xb + (size_t)myidx * 3;
    float* ob = out + (size_t)center * CH * NS + lane;
    __builtin_nontemporal_store(pp[0] - cx, ob + 0 * NS);
    __builtin_nontemporal_store(pp[1] - cy, ob + 1 * NS);
    __builtin_nontemporal_store(pp[2] - cz, ob + 2 * NS);

    const float4* frow = (const float4*)(ft + ((size_t)b * NN + myidx) * CC);
#pragma unroll
    for (int p = 0; p < 2; ++p) {
        float4 v[8];
#pragma unroll
        for (int i = 0; i < 8; ++i) v[i] = frow[8 * p + i];  // 8 dwordx4 in flight
        float* o2 = ob + (size_t)(3 + 32 * p) * NS;
#pragma unroll
        for (int i = 0; i < 8; ++i) {                        // 256B-coalesced stores
            __builtin_nontemporal_store(v[i].x, o2 + (size_t)(4 * i + 0) * NS);
            __builtin_nontemporal_store(v[i].y, o2 + (size_t)(4 * i + 1) * NS);
            __builtin_nontemporal_store(v[i].z, o2 + (size_t)(4 * i + 2) * NS);
            __builtin_nontemporal_store(v[i].w, o2 + (size_t)(4 * i + 3) * NS);
        }
    }
}

// ---------- Fallback (ws too small): round-1 direct-gather kernel ----------
__global__ __launch_bounds__(256, 4) void pn2_group_kernel(
    const float* __restrict__ xyz, const float* __restrict__ new_xyz,
    const float* __restrict__ features, float* __restrict__ out)
{
    __shared__ int sidx[4][NS];
    const int lane = threadIdx.x & 63;
    const int wave = threadIdx.x >> 6;
    const int center = blockIdx.x * 4 + wave;
    const int b = center >> 11;
    const int j = center & (NP - 1);
    const float r2 = 0.04f;
    const float* q = new_xyz + ((size_t)b * NP + j) * 3;
    const float cx = q[0], cy = q[1], cz = q[2];
    int* widx = sidx[wave];
    int found = 0;
    for (int it = 0; it < NN / 64; ++it) {
        const int n = it * 64 + lane;
        const float* p = xyz + ((size_t)b * NN + n) * 3;
        const float dx = p[0] - cx, dy = p[1] - cy, dz = p[2] - cz;
        const float d2 = __fadd_rn(__fadd_rn(__fmul_rn(dx, dx), __fmul_rn(dy, dy)),
                                   __fmul_rn(dz, dz));
        const bool within = d2 < r2;
        const unsigned long long mask = __ballot(within);
        const int pos = found + (int)__popcll(mask & ((1ull << lane) - 1ull));
        if (within && pos < NS) widx[pos] = n;
        found += (int)__popcll(mask);
        if (found >= NS) break;
    }
    int myidx = 0;
    if (found > 0) {
        const int first = widx[0];
        myidx = (lane < found) ? widx[lane] : first;
    }
    const float* pp = xyz + ((size_t)b * NN + myidx) * 3;
    float* ob = out + (((size_t)b * NP + j) * (size_t)CH) * NS + lane;
    ob[0 * NS] = pp[0] - cx;
    ob[1 * NS] = pp[1] - cy;
    ob[2 * NS] = pp[2] - cz;
    const float* fb = features + (size_t)b * CC * NN + myidx;
#pragma unroll 8
    for (int c = 0; c < CC; ++c) ob[(size_t)(3 + c) * NS] = fb[(size_t)c * NN];
}

extern "C" void kernel_launch(void* const* d_in, const int* in_sizes, int n_in,
                              void* d_out, int out_size, void* d_ws, size_t ws_size,
                              hipStream_t stream) {
    const float* xyz      = (const float*)d_in[0];
    const float* new_xyz  = (const float*)d_in[1];
    const float* features = (const float*)d_in[2];
    float* out = (float*)d_out;

    const size_t ft_bytes = (size_t)BB * NN * CC * sizeof(float);   // 16.8 MB

    if (ws_size >= ft_bytes) {
        float* ft = (float*)d_ws;
        pn2_transpose_kernel<<<BB * 256, 256, 0, stream>>>(features, ft);
        pn2_qg_kernel<<<BB * NP / 4, 256, 0, stream>>>(xyz, new_xyz, ft, out);
    } else {
        pn2_group_kernel<<<BB * NP / 4, 256, 0, stream>>>(xyz, new_xyz, features, out);
    }
}

// Round 5
// 49.250 us; speedup vs baseline: 2.9001x; 1.1052x over previous
//
#include <hip/hip_runtime.h>

// PointNet++ grouping: ball query (radius 0.2, nsample 64) + gather + concat.
// Shapes fixed by setup_inputs(): B=4, N=16384, npoint=2048, C=64.
// out[b][j][c][s]: c in [0,3) = xyz[idx]-new_xyz, c in [3,67) = features[c-3][idx].
//
// Pipeline:
//   Kernel 1: transpose features (B,C,N) -> ft (B,N,C) in ws (BW-bound).
//   Kernel 2: fused query + COOPERATIVE gather. Ball query leaves idx in
//     LDS; then each 256B ft row is read by 16 lanes x 16B (one dwordx4
//     instruction covers 4 whole rows => 16 cache-line lookups/instr instead
//     of 64 for the lane-per-row gather: 4x less TA serialization, which was
//     co-critical with HBM write BW). Data is lane-transposed through an
//     XOR-swizzled 8KB/wave LDS tile (wave-internal, no barriers), then
//     written as 256B-coalesced nontemporal stores.

#define BB 4
#define NN 16384
#define NP 2048
#define CC 64
#define NS 64
#define CH (3 + CC)
#define NCHUNK (NN / 256)   // 64 chunks of 256 points

// ---------- Kernel 1: features (B,C,N) -> ft (B,N,C) ----------
__global__ __launch_bounds__(256) void pn2_transpose_kernel(
    const float* __restrict__ f, float* __restrict__ ft)
{
    __shared__ float tile[CC][65];           // +1 pad: conflict-free both ways
    const int b   = blockIdx.x >> 8;         // N/64 = 256 tiles per batch
    const int n0  = (blockIdx.x & 255) << 6;
    const int col = threadIdx.x & 63;
    const int r4  = threadIdx.x >> 6;        // 0..3
    const float* src = f + (size_t)b * CC * NN;
#pragma unroll
    for (int i = 0; i < 16; ++i) {
        const int c = r4 + i * 4;
        tile[c][col] = __builtin_nontemporal_load(&src[(size_t)c * NN + n0 + col]);
    }
    __syncthreads();
    float* dst = ft + ((size_t)b * NN + n0) * CC;
#pragma unroll
    for (int i = 0; i < 16; ++i) {
        const int n = r4 + i * 4;
        dst[(size_t)n * CC + col] = tile[col][n];        // coalesced along c
    }
}

// ---------- Kernel 2: fused ball query + cooperative gather ----------
__global__ __launch_bounds__(256, 4) void pn2_qg_kernel(
    const float* __restrict__ xyz,       // (B, N, 3)
    const float* __restrict__ new_xyz,   // (B, NP, 3)
    const float* __restrict__ ft,        // ws: (B, N, C)
    float* __restrict__ out)             // (B, NP, CH, NS)
{
    __shared__ int sidx[4][NS];
    __shared__ float4 stile[4][32 * 16];     // 8KB per wave: [32 samples][16 quads]

    const int lane = threadIdx.x & 63;
    const int wave = threadIdx.x >> 6;
    const int center = blockIdx.x * 4 + wave;   // 0 .. B*NP-1
    const int b = center >> 11;
    const int j = center & (NP - 1);

    const float r2 = 0.04f;                     // f32(0.2*0.2)
    const float* q = new_xyz + ((size_t)b * NP + j) * 3;
    const float cx = q[0], cy = q[1], cz = q[2];

    const float* xb = xyz + (size_t)b * NN * 3;
    const float4* x4 = (const float4*)xb;
    int* widx = sidx[wave];

    // ---- query: 4 points/lane (48B = 3x float4), prefetch one chunk ahead
    const int base = 3 * lane;
    const unsigned long long low = (1ull << lane) - 1ull;
    int found = 0;
    int it = 0;
    float4 A = x4[base], Bv = x4[base + 1], Cv = x4[base + 2];

    while (true) {
        const int nit = (it + 1 < NCHUNK) ? it + 1 : it;
        const size_t nb = (size_t)nit * 192 + base;
        float4 nA = x4[nb], nB = x4[nb + 1], nC = x4[nb + 2];

        const int n0 = it * 256 + 4 * lane;
        const float px[4] = {A.x, A.w, Bv.z, Cv.y};
        const float py[4] = {A.y, Bv.x, Bv.w, Cv.z};
        const float pz[4] = {A.z, Bv.y, Cv.x, Cv.w};
        bool in[4];
        unsigned long long m[4];
#pragma unroll
        for (int k = 0; k < 4; ++k) {
            const float dx = px[k] - cx;
            const float dy = py[k] - cy;
            const float dz = pz[k] - cz;
            // match numpy: plain f32 mul/add, left-to-right, NO fma contraction
            const float d2 = __fadd_rn(__fadd_rn(__fmul_rn(dx, dx), __fmul_rn(dy, dy)),
                                       __fmul_rn(dz, dz));
            in[k] = d2 < r2;
            m[k] = __ballot(in[k]);
        }
        int pos = found
                + (int)__popcll(m[0] & low) + (int)__popcll(m[1] & low)
                + (int)__popcll(m[2] & low) + (int)__popcll(m[3] & low);
#pragma unroll
        for (int k = 0; k < 4; ++k) {
            if (in[k]) {
                if (pos < NS) widx[pos] = n0 + k;
                ++pos;
            }
        }
        found += (int)(__popcll(m[0]) + __popcll(m[1])
                     + __popcll(m[2]) + __popcll(m[3]));     // wave-uniform
        if (found >= NS || it == NCHUNK - 1) break;          // uniform branch
        A = nA; Bv = nB; Cv = nC; ++it;
    }

    // ref fill semantics: pad with first found idx, 0 if none found
    int myidx = 0;
    if (found > 0) {
        const int first = widx[0];
        myidx = (lane < found) ? widx[lane] : first;
    }
    widx[lane] = myidx;   // full 64-slot idx table for the cooperative gather

    // ---- xyz channels (lane = sample slot; 256B-coalesced NT stores)
    const float* pp = xb + (size_t)myidx * 3;
    float* ob = out + (size_t)center * CH * NS;
    __builtin_nontemporal_store(pp[0] - cx, ob + 0 * NS + lane);
    __builtin_nontemporal_store(pp[1] - cy, ob + 1 * NS + lane);
    __builtin_nontemporal_store(pp[2] - cz, ob + 2 * NS + lane);

    // ---- cooperative feature gather: 16 lanes per 256B row, LDS transpose
    const float* ftb = ft + (size_t)b * NN * CC;
    float4* tw = stile[wave];
    const int sub  = lane & 15;   // 16B chunk within a row
    const int rsub = lane >> 4;   // which of 4 rows this instruction covers
    const int s_loc = lane & 31;  // store phase: sample within half
    const int which = lane >> 5;  // store phase: channel-quad parity

#pragma unroll
    for (int h = 0; h < 2; ++h) {
        int ridx[8];
#pragma unroll
        for (int i = 0; i < 8; ++i) ridx[i] = widx[32 * h + 4 * i + rsub];
        float4 v[8];
#pragma unroll
        for (int i = 0; i < 8; ++i)   // 8 dwordx4, contiguous 256B lane groups
            v[i] = *(const float4*)(ftb + (size_t)ridx[i] * CC + 4 * sub);
#pragma unroll
        for (int i = 0; i < 8; ++i) { // XOR-swizzled stage (2-way = free)
            const int s = 4 * i + rsub;
            tw[s * 16 + (sub ^ (s & 15))] = v[i];
        }
#pragma unroll
        for (int t = 0; t < 8; ++t) {
            const int cq = 2 * t + which;                       // quad 0..15
            const float4 u = tw[s_loc * 16 + (cq ^ (s_loc & 15))];
            float* o = ob + (size_t)(3 + 4 * cq) * NS + 32 * h + s_loc;
            __builtin_nontemporal_store(u.x, o + 0 * NS);
            __builtin_nontemporal_store(u.y, o + 1 * NS);
            __builtin_nontemporal_store(u.z, o + 2 * NS);
            __builtin_nontemporal_store(u.w, o + 3 * NS);
        }
    }
}

// ---------- Fallback (ws too small): round-1 direct-gather kernel ----------
__global__ __launch_bounds__(256, 4) void pn2_group_kernel(
    const float* __restrict__ xyz, const float* __restrict__ new_xyz,
    const float* __restrict__ features, float* __restrict__ out)
{
    __shared__ int sidx[4][NS];
    const int lane = threadIdx.x & 63;
    const int wave = threadIdx.x >> 6;
    const int center = blockIdx.x * 4 + wave;
    const int b = center >> 11;
    const int j = center & (NP - 1);
    const float r2 = 0.04f;
    const float* q = new_xyz + ((size_t)b * NP + j) * 3;
    const float cx = q[0], cy = q[1], cz = q[2];
    int* widx = sidx[wave];
    int found = 0;
    for (int it = 0; it < NN / 64; ++it) {
        const int n = it * 64 + lane;
        const float* p = xyz + ((size_t)b * NN + n) * 3;
        const float dx = p[0] - cx, dy = p[1] - cy, dz = p[2] - cz;
        const float d2 = __fadd_rn(__fadd_rn(__fmul_rn(dx, dx), __fmul_rn(dy, dy)),
                                   __fmul_rn(dz, dz));
        const bool within = d2 < r2;
        const unsigned long long mask = __ballot(within);
        const int pos = found + (int)__popcll(mask & ((1ull << lane) - 1ull));
        if (within && pos < NS) widx[pos] = n;
        found += (int)__popcll(mask);
        if (found >= NS) break;
    }
    int myidx = 0;
    if (found > 0) {
        const int first = widx[0];
        myidx = (lane < found) ? widx[lane] : first;
    }
    const float* pp = xyz + ((size_t)b * NN + myidx) * 3;
    float* ob = out + (((size_t)b * NP + j) * (size_t)CH) * NS + lane;
    ob[0 * NS] = pp[0] - cx;
    ob[1 * NS] = pp[1] - cy;
    ob[2 * NS] = pp[2] - cz;
    const float* fb = features + (size_t)b * CC * NN + myidx;
#pragma unroll 8
    for (int c = 0; c < CC; ++c) ob[(size_t)(3 + c) * NS] = fb[(size_t)c * NN];
}

extern "C" void kernel_launch(void* const* d_in, const int* in_sizes, int n_in,
                              void* d_out, int out_size, void* d_ws, size_t ws_size,
                              hipStream_t stream) {
    const float* xyz      = (const float*)d_in[0];
    const float* new_xyz  = (const float*)d_in[1];
    const float* features = (const float*)d_in[2];
    float* out = (float*)d_out;

    const size_t ft_bytes = (size_t)BB * NN * CC * sizeof(float);   // 16.8 MB

    if (ws_size >= ft_bytes) {
        float* ft = (float*)d_ws;
        pn2_transpose_kernel<<<BB * 256, 256, 0, stream>>>(features, ft);
        pn2_qg_kernel<<<BB * NP / 4, 256, 0, stream>>>(xyz, new_xyz, ft, out);
    } else {
        pn2_group_kernel<<<BB * NP / 4, 256, 0, stream>>>(xyz, new_xyz, features, out);
    }
}

// Round 7
// 46.087 us; speedup vs baseline: 3.0991x; 1.0686x over previous
//
#include <hip/hip_runtime.h>

// PointNet++ grouping: ball query (radius 0.2, nsample 64) + gather + concat.
// Shapes fixed by setup_inputs(): B=4, N=16384, npoint=2048, C=64.
// out[b][j][c][s]: c in [0,3) = xyz[idx]-new_xyz, c in [3,67) = features[c-3][idx].
//
// Structure (round 7 = round 6 with a compile fix):
//   Kernel 1: transpose features (B,C,N) -> ft (B,N,C) in ws, XCD-pinned so
//     batch b's ft is write-allocated into XCD pair b's L2.
//   Kernel 2: fused query + cooperative gather, XCD-pinned to the same pair.
//     Gather: 16 lanes x 16B per 256B ft row (16 line-lookups/instr), lane
//     transpose through a [32][65]-float LDS tile (<=2-way bank alias both
//     sides = free), then 16 x dwordx4 NT stores per wave (1024B each)
//     instead of 64 scalar stores — VMEM instruction count is co-critical
//     with the HBM write drain.
//   Fix vs round 6: __builtin_nontemporal_store requires a clang vector
//     type, not HIP_vector_type — use ext_vector_type(4) float.

#define BB 4
#define NN 16384
#define NP 2048
#define CC 64
#define NS 64
#define CH (3 + CC)
#define NCHUNK (NN / 256)   // 64 chunks of 256 points
#define ST 65               // LDS tile row stride (floats)

typedef float f32x4 __attribute__((ext_vector_type(4)));

// ---------- Kernel 1: features (B,C,N) -> ft (B,N,C), XCD-pinned ----------
__global__ __launch_bounds__(256) void pn2_transpose_kernel(
    const float* __restrict__ f, float* __restrict__ ft)
{
    __shared__ float tile[CC][65];           // +1 pad: conflict-free both ways
    const int g = blockIdx.x;                // 1024 blocks
    const int xcd = g & 7;
    const int b = xcd >> 1;                  // batch pinned to XCD pair
    const int tidx = ((xcd & 1) << 7) + (g >> 3);   // 0..255
    const int n0 = tidx << 6;
    const int col = threadIdx.x & 63;
    const int r4  = threadIdx.x >> 6;        // 0..3
    const float* src = f + (size_t)b * CC * NN;
#pragma unroll
    for (int i = 0; i < 16; ++i) {
        const int c = r4 + i * 4;
        tile[c][col] = __builtin_nontemporal_load(&src[(size_t)c * NN + n0 + col]);
    }
    __syncthreads();
    float* dst = ft + ((size_t)b * NN + n0) * CC;
#pragma unroll
    for (int i = 0; i < 16; ++i) {
        const int n = r4 + i * 4;
        dst[(size_t)n * CC + col] = tile[col][n];        // coalesced along c
    }
}

// ---------- Kernel 2: fused ball query + cooperative gather ----------
__global__ __launch_bounds__(256, 4) void pn2_qg_kernel(
    const float* __restrict__ xyz,       // (B, N, 3)
    const float* __restrict__ new_xyz,   // (B, NP, 3)
    const float* __restrict__ ft,        // ws: (B, N, C)
    float* __restrict__ out)             // (B, NP, CH, NS)
{
    __shared__ int sidx[4][NS];
    __shared__ float stile[4][32 * ST];      // 8.3KB/wave transpose tile

    const int lane = threadIdx.x & 63;
    const int wave = threadIdx.x >> 6;

    // XCD batch pinning: XCD pair (2b,2b+1) handles batch b (matches the
    // transpose kernel's write placement). Bijective over 2048 blocks.
    const int g = blockIdx.x;
    const int xcd = g & 7;
    const int cg = ((xcd >> 1) << 9) + ((xcd & 1) << 8) + (g >> 3);
    const int center = cg * 4 + wave;           // 0 .. B*NP-1
    const int b = center >> 11;
    const int j = center & (NP - 1);

    const float r2 = 0.04f;                     // f32(0.2*0.2)
    const float* q = new_xyz + ((size_t)b * NP + j) * 3;
    const float cx = q[0], cy = q[1], cz = q[2];

    const float* xb = xyz + (size_t)b * NN * 3;
    const float4* x4 = (const float4*)xb;
    int* widx = sidx[wave];

    // ---- query: 4 points/lane (48B = 3x float4), prefetch one chunk ahead
    const int base = 3 * lane;
    const unsigned long long low = (1ull << lane) - 1ull;
    int found = 0;
    int it = 0;
    float4 A = x4[base], Bv = x4[base + 1], Cv = x4[base + 2];

    while (true) {
        const int nit = (it + 1 < NCHUNK) ? it + 1 : it;
        const size_t nb = (size_t)nit * 192 + base;
        float4 nA = x4[nb], nB = x4[nb + 1], nC = x4[nb + 2];

        const int n0 = it * 256 + 4 * lane;
        const float px[4] = {A.x, A.w, Bv.z, Cv.y};
        const float py[4] = {A.y, Bv.x, Bv.w, Cv.z};
        const float pz[4] = {A.z, Bv.y, Cv.x, Cv.w};
        bool in[4];
        unsigned long long m[4];
#pragma unroll
        for (int k = 0; k < 4; ++k) {
            const float dx = px[k] - cx;
            const float dy = py[k] - cy;
            const float dz = pz[k] - cz;
            // match numpy: plain f32 mul/add, left-to-right, NO fma contraction
            const float d2 = __fadd_rn(__fadd_rn(__fmul_rn(dx, dx), __fmul_rn(dy, dy)),
                                       __fmul_rn(dz, dz));
            in[k] = d2 < r2;
            m[k] = __ballot(in[k]);
        }
        int pos = found
                + (int)__popcll(m[0] & low) + (int)__popcll(m[1] & low)
                + (int)__popcll(m[2] & low) + (int)__popcll(m[3] & low);
#pragma unroll
        for (int k = 0; k < 4; ++k) {
            if (in[k]) {
                if (pos < NS) widx[pos] = n0 + k;
                ++pos;
            }
        }
        found += (int)(__popcll(m[0]) + __popcll(m[1])
                     + __popcll(m[2]) + __popcll(m[3]));     // wave-uniform
        if (found >= NS || it == NCHUNK - 1) break;          // uniform branch
        A = nA; Bv = nB; Cv = nC; ++it;
    }

    // ref fill semantics: pad with first found idx, 0 if none found
    int myidx = 0;
    if (found > 0) {
        const int first = widx[0];
        myidx = (lane < found) ? widx[lane] : first;
    }
    widx[lane] = myidx;   // full 64-slot idx table for the cooperative gather

    // ---- xyz channels (lane = sample slot; 256B-coalesced NT stores)
    const float* pp = xb + (size_t)myidx * 3;
    float* ob = out + (size_t)center * CH * NS;
    __builtin_nontemporal_store(pp[0] - cx, ob + 0 * NS + lane);
    __builtin_nontemporal_store(pp[1] - cy, ob + 1 * NS + lane);
    __builtin_nontemporal_store(pp[2] - cz, ob + 2 * NS + lane);

    // ---- cooperative feature gather with dwordx4 stores
    // load side:  lane = (rsub, sub): 16 lanes x 16B cover one 256B row,
    //             one dwordx4 instr covers 4 rows.
    // store side: lane = (cc8, sq): f32x4 = samples 4sq..4sq+3 of channel
    //             8t+cc8; one dwordx4 instr covers 8 channel-row 128B segments.
    const float* ftb = ft + (size_t)b * NN * CC;
    float* tw = stile[wave];
    const int sub  = lane & 15;   // 16B chunk within a row
    const int rsub = lane >> 4;   // which of 4 rows this instr covers
    const int sq   = lane & 7;    // sample quad within half
    const int cc8  = lane >> 3;   // channel offset within group of 8

#pragma unroll
    for (int h = 0; h < 2; ++h) {
        int ridx[8];
#pragma unroll
        for (int i = 0; i < 8; ++i) ridx[i] = widx[32 * h + 4 * i + rsub];
        float4 v[8];
#pragma unroll
        for (int i = 0; i < 8; ++i)   // 8 dwordx4, contiguous 256B lane groups
            v[i] = *(const float4*)(ftb + (size_t)ridx[i] * CC + 4 * sub);
#pragma unroll
        for (int i = 0; i < 8; ++i) { // tile[sample][channel], <=2-way banks
            float* tr = tw + (4 * i + rsub) * ST + 4 * sub;
            tr[0] = v[i].x; tr[1] = v[i].y; tr[2] = v[i].z; tr[3] = v[i].w;
        }
#pragma unroll
        for (int t = 0; t < 8; ++t) { // 8 dwordx4 NT stores per half
            const int c = 8 * t + cc8;
            f32x4 u;
            u.x = tw[(4 * sq + 0) * ST + c];
            u.y = tw[(4 * sq + 1) * ST + c];
            u.z = tw[(4 * sq + 2) * ST + c];
            u.w = tw[(4 * sq + 3) * ST + c];
            float* o = ob + (size_t)(3 + c) * NS + 32 * h + 4 * sq;  // 16B aligned
            __builtin_nontemporal_store(u, (f32x4*)o);
        }
    }
}

// ---------- Fallback (ws too small): round-1 direct-gather kernel ----------
__global__ __launch_bounds__(256, 4) void pn2_group_kernel(
    const float* __restrict__ xyz, const float* __restrict__ new_xyz,
    const float* __restrict__ features, float* __restrict__ out)
{
    __shared__ int sidx[4][NS];
    const int lane = threadIdx.x & 63;
    const int wave = threadIdx.x >> 6;
    const int center = blockIdx.x * 4 + wave;
    const int b = center >> 11;
    const int j = center & (NP - 1);
    const float r2 = 0.04f;
    const float* q = new_xyz + ((size_t)b * NP + j) * 3;
    const float cx = q[0], cy = q[1], cz = q[2];
    int* widx = sidx[wave];
    int found = 0;
    for (int it = 0; it < NN / 64; ++it) {
        const int n = it * 64 + lane;
        const float* p = xyz + ((size_t)b * NN + n) * 3;
        const float dx = p[0] - cx, dy = p[1] - cy, dz = p[2] - cz;
        const float d2 = __fadd_rn(__fadd_rn(__fmul_rn(dx, dx), __fmul_rn(dy, dy)),
                                   __fmul_rn(dz, dz));
        const bool within = d2 < r2;
        const unsigned long long mask = __ballot(within);
        const int pos = found + (int)__popcll(mask & ((1ull << lane) - 1ull));
        if (within && pos < NS) widx[pos] = n;
        found += (int)__popcll(mask);
        if (found >= NS) break;
    }
    int myidx = 0;
    if (found > 0) {
        const int first = widx[0];
        myidx = (lane < found) ? widx[lane] : first;
    }
    const float* pp = xyz + ((size_t)b * NN + myidx) * 3;
    float* ob = out + (((size_t)b * NP + j) * (size_t)CH) * NS + lane;
    ob[0 * NS] = pp[0] - cx;
    ob[1 * NS] = pp[1] - cy;
    ob[2 * NS] = pp[2] - cz;
    const float* fb = features + (size_t)b * CC * NN + myidx;
#pragma unroll 8
    for (int c = 0; c < CC; ++c) ob[(size_t)(3 + c) * NS] = fb[(size_t)c * NN];
}

extern "C" void kernel_launch(void* const* d_in, const int* in_sizes, int n_in,
                              void* d_out, int out_size, void* d_ws, size_t ws_size,
                              hipStream_t stream) {
    const float* xyz      = (const float*)d_in[0];
    const float* new_xyz  = (const float*)d_in[1];
    const float* features = (const float*)d_in[2];
    float* out = (float*)d_out;

    const size_t ft_bytes = (size_t)BB * NN * CC * sizeof(float);   // 16.8 MB

    if (ws_size >= ft_bytes) {
        float* ft = (float*)d_ws;
        pn2_transpose_kernel<<<BB * 256, 256, 0, stream>>>(features, ft);
        pn2_qg_kernel<<<BB * NP / 4, 256, 0, stream>>>(xyz, new_xyz, ft, out);
    } else {
        pn2_group_kernel<<<BB * NP / 4, 256, 0, stream>>>(xyz, new_xyz, features, out);
    }
}